// Round 7
// baseline (282.431 us; speedup 1.0000x reference)
//
#include <hip/hip_runtime.h>
#include <math.h>

// Problem constants
#define Bsz 2
#define Tsz 2048
#define Csz 768
#define Hsz 12
#define C3  2304      // 3*C
#define WIN 256
#define LN_EPS 1e-5f

// Q pre-scale: D^-0.5 * log2(e), folded into the QKV GEMM epilogue so the
// attention kernel works in the exp2 domain with no per-element multiplies.
#define QSCALE 0.1803368801111137f

typedef short bf16x8 __attribute__((ext_vector_type(8)));  // 8 bf16 (4 VGPRs)
typedef float f32x4  __attribute__((ext_vector_type(4)));

// fp32 -> bf16 round-to-nearest-even
__device__ __forceinline__ unsigned short f2b(float f) {
    unsigned int u = __float_as_uint(f);
    u = (u + 0x7fffu + ((u >> 16) & 1u)) >> 16;
    return (unsigned short)u;
}

// raw v_exp_f32 (exp2). ocml exp2f without fast-math adds ~5 insts of
// denormal fixup; inputs here are |x| <~ 12, nothing denormal matters.
__device__ __forceinline__ float fast_exp2(float x) {
    float r;
    asm("v_exp_f32 %0, %1" : "=v"(r) : "v"(x));
    return r;
}

// ---------------------------------------------------------------------------
// Elementwise fp32 -> bf16 (4 elems/thread)
// ---------------------------------------------------------------------------
__global__ __launch_bounds__(256) void convert_bf16(
    const float* __restrict__ src, unsigned short* __restrict__ dst, int n4)
{
    int idx = blockIdx.x * 256 + threadIdx.x;
    if (idx >= n4) return;
    float4 v = *(const float4*)(src + (size_t)idx * 4);
    unsigned int lo = (unsigned int)f2b(v.x) | ((unsigned int)f2b(v.y) << 16);
    unsigned int hi = (unsigned int)f2b(v.z) | ((unsigned int)f2b(v.w) << 16);
    uint2 o; o.x = lo; o.y = hi;
    *(uint2*)(dst + (size_t)idx * 4) = o;
}

// ---------------------------------------------------------------------------
// fp32 [K][N] -> bf16 [N][K] (transpose + convert)
// ---------------------------------------------------------------------------
__global__ __launch_bounds__(256) void transpose_conv(
    const float* __restrict__ src, unsigned short* __restrict__ dst, int K, int N)
{
    __shared__ float tile[32][33];
    const int n0 = blockIdx.x * 32, k0 = blockIdx.y * 32;
    const int tx = threadIdx.x & 31, ty = threadIdx.x >> 5;   // 32 x 8
    #pragma unroll
    for (int p = 0; p < 4; ++p)
        tile[ty + p * 8][tx] = src[(size_t)(k0 + ty + p * 8) * N + n0 + tx];
    __syncthreads();
    #pragma unroll
    for (int p = 0; p < 4; ++p)
        dst[(size_t)(n0 + ty + p * 8) * K + k0 + tx] = f2b(tile[tx][ty + p * 8]);
}

// ---------------------------------------------------------------------------
// V transpose: qkvb bf16 [B*T][3C] -> VT bf16 [B*H][64][T]
// ---------------------------------------------------------------------------
__global__ __launch_bounds__(256) void transpose_v(
    const unsigned short* __restrict__ qkv, unsigned short* __restrict__ VT)
{
    __shared__ unsigned short tile[32][33];
    const int bh = blockIdx.z;
    const int b = bh / Hsz, h = bh % Hsz;
    const int t0 = blockIdx.x * 32, d0 = blockIdx.y * 32;
    const int tx = threadIdx.x & 31, ty = threadIdx.x >> 5;
    #pragma unroll
    for (int p = 0; p < 4; ++p) {
        int t = t0 + ty + p * 8;
        tile[ty + p * 8][tx] =
            qkv[(size_t)(b * Tsz + t) * C3 + 2 * Csz + h * 64 + d0 + tx];
    }
    __syncthreads();
    #pragma unroll
    for (int p = 0; p < 4; ++p) {
        int d = d0 + ty + p * 8;
        VT[((size_t)bh * 64 + d) * Tsz + t0 + tx] = tile[tx][ty + p * 8];
    }
}

// ---------------------------------------------------------------------------
// fsel[r] = 0.5 + 0.5*sigmoid(mamba_scale * dot(LN(mamba_raw[r]), sel_w) + sel_b)
// ---------------------------------------------------------------------------
__global__ __launch_bounds__(256) void sel_kernel(
    const float* __restrict__ mr, const float* __restrict__ ln_w,
    const float* __restrict__ ln_b, const float* __restrict__ scale_p,
    const float* __restrict__ sel_w, const float* __restrict__ sel_b,
    float* __restrict__ sel)
{
    __shared__ float red1[256];
    __shared__ float red2[256];
    __shared__ float mu_sh, rstd_sh;

    const int r = blockIdx.x;
    const int tid = threadIdx.x;
    const float* row = mr + (size_t)r * Csz;

    float s = 0.f, s2 = 0.f;
    for (int c = tid; c < Csz; c += 256) {
        float x = row[c];
        s += x; s2 += x * x;
    }
    red1[tid] = s; red2[tid] = s2;
    __syncthreads();
    for (int st = 128; st > 0; st >>= 1) {
        if (tid < st) { red1[tid] += red1[tid + st]; red2[tid] += red2[tid + st]; }
        __syncthreads();
    }
    if (tid == 0) {
        float mu = red1[0] * (1.f / Csz);
        float var = red2[0] * (1.f / Csz) - mu * mu;
        mu_sh = mu;
        rstd_sh = rsqrtf(var + LN_EPS);
    }
    __syncthreads();
    const float mu = mu_sh, rstd = rstd_sh;

    float dot = 0.f;
    for (int c = tid; c < Csz; c += 256) {
        float xn = (row[c] - mu) * rstd * ln_w[c] + ln_b[c];
        dot += xn * sel_w[c];
    }
    red1[tid] = dot;
    __syncthreads();
    for (int st = 128; st > 0; st >>= 1) {
        if (tid < st) red1[tid] += red1[tid + st];
        __syncthreads();
    }
    if (tid == 0) {
        float z = scale_p[0] * red1[0] + sel_b[0];
        sel[r] = 0.5f + 0.5f / (1.f + __expf(-z));
    }
}

// ---------------------------------------------------------------------------
// bf16 MFMA GEMM, B^T input: C[M,N] = A[M,K] @ BT[N,K]^T + bias
// cols < scale_cols additionally scaled by QSCALE (folds attention q-scale,
// applied after bias -- matches reference (x@W+b)*scale).
// ---------------------------------------------------------------------------
template<int OUT_BF16>
__global__ __launch_bounds__(256) void gemm_bt_mfma(
    const unsigned short* __restrict__ A, const unsigned short* __restrict__ BT,
    const float* __restrict__ bias, void* __restrict__ Cout,
    int M, int N, int K, int scale_cols)
{
    __shared__ unsigned short As[128 * 32];
    __shared__ unsigned short Bs[128 * 32];

    const int tid = threadIdx.x;
    const int lane = tid & 63, widx = tid >> 6;
    const int lm = lane & 15, quad = lane >> 4;
    const int wm = widx >> 1, wn = widx & 1;
    const int m0 = blockIdx.y * 128, n0 = blockIdx.x * 128;

    f32x4 acc[4][4];
    #pragma unroll
    for (int mt = 0; mt < 4; ++mt)
        #pragma unroll
        for (int nt = 0; nt < 4; ++nt)
            acc[mt][nt] = f32x4{0.f, 0.f, 0.f, 0.f};

    int rowS[2], cS[2];
    #pragma unroll
    for (int t = 0; t < 2; ++t) {
        int idx = t * 256 + tid;
        rowS[t] = idx >> 2;
        cS[t] = idx & 3;
    }

    bf16x8 pa[2], pb[2];
    #pragma unroll
    for (int t = 0; t < 2; ++t) {
        pa[t] = *(const bf16x8*)(A + (size_t)(m0 + rowS[t]) * K + cS[t] * 8);
        pb[t] = *(const bf16x8*)(BT + (size_t)(n0 + rowS[t]) * K + cS[t] * 8);
    }

    const int nk = K / 32;
    for (int kt = 0; kt < nk; ++kt) {
        __syncthreads();
        #pragma unroll
        for (int t = 0; t < 2; ++t) {
            *(bf16x8*)(&As[rowS[t] * 32 + ((cS[t] ^ ((rowS[t] >> 1) & 3)) << 3)]) = pa[t];
            *(bf16x8*)(&Bs[rowS[t] * 32 + ((cS[t] ^ ((rowS[t] >> 1) & 3)) << 3)]) = pb[t];
        }
        __syncthreads();
        if (kt + 1 < nk) {
            int k0 = (kt + 1) * 32;
            #pragma unroll
            for (int t = 0; t < 2; ++t) {
                pa[t] = *(const bf16x8*)(A + (size_t)(m0 + rowS[t]) * K + k0 + cS[t] * 8);
                pb[t] = *(const bf16x8*)(BT + (size_t)(n0 + rowS[t]) * K + k0 + cS[t] * 8);
            }
        }
        bf16x8 af[4], bf[4];
        #pragma unroll
        for (int mt = 0; mt < 4; ++mt) {
            int m = wm * 64 + mt * 16 + lm;
            af[mt] = *(const bf16x8*)(&As[m * 32 + ((quad ^ ((m >> 1) & 3)) << 3)]);
        }
        #pragma unroll
        for (int nt = 0; nt < 4; ++nt) {
            int n = wn * 64 + nt * 16 + lm;
            bf[nt] = *(const bf16x8*)(&Bs[n * 32 + ((quad ^ ((n >> 1) & 3)) << 3)]);
        }
        #pragma unroll
        for (int mt = 0; mt < 4; ++mt)
            #pragma unroll
            for (int nt = 0; nt < 4; ++nt)
                acc[mt][nt] = __builtin_amdgcn_mfma_f32_16x16x32_bf16(
                    af[mt], bf[nt], acc[mt][nt], 0, 0, 0);
    }

    float bv[4], scl[4];
    #pragma unroll
    for (int nt = 0; nt < 4; ++nt) {
        bv[nt] = bias[n0 + wn * 64 + nt * 16 + lm];
        scl[nt] = ((n0 + wn * 64 + nt * 16) < scale_cols) ? QSCALE : 1.0f;
    }

    #pragma unroll
    for (int mt = 0; mt < 4; ++mt) {
        #pragma unroll
        for (int nt = 0; nt < 4; ++nt) {
            int col = n0 + wn * 64 + nt * 16 + lm;
            #pragma unroll
            for (int r = 0; r < 4; ++r) {
                int row = m0 + wm * 64 + mt * 16 + quad * 4 + r;
                float v = (acc[mt][nt][r] + bv[nt]) * scl[nt];
                if (OUT_BF16)
                    ((unsigned short*)Cout)[(size_t)row * N + col] = f2b(v);
                else
                    ((float*)Cout)[(size_t)row * N + col] = v;
            }
        }
    }
}

// ---------------------------------------------------------------------------
// MFMA flash attention, dual softmax, NO-MAX variant.
// R6 restructure: 512-thread blocks, 6 GLOBAL waves + 2 LOCAL waves.
// Combines the two separately-measured wins:
//  - single-branch wave body = 52 VGPR (R4-measured) -> 8 waves/SIMD class
//    -> up to 32 resident waves/CU (2x the dual-branch body's 16, which was
//    class-locked at 72-76 VGPR).
//  - global waves step 6: ceil(n/6) latency-chain traversals per wave, 1.5x
//    FEWER than the dual-branch ceil(n/4). (R4's regression came from step 3
//    = 1.33x MORE; that run calibrated the traversal->time sensitivity.)
// Local waves (widx 6,7) recompute their own QK^T for the <=5 local tiles
// (<=3 each; 8 extra MFMA/tile, measured noise in R4).
// NO cross-tile register prefetch (compiler re-sinks it, R5), NO
// launch_bounds min-occupancy arg (forces spill, R1/R3).
// Merge: waves 1..7 write slots 0..6 (global 0..4, local 5..6); wave 0
// combines + epilogue. Pbuf (8x16x72 ushort = 18432 B) and Mrg (7x16x66 f32
// = 29568 B) overlaid; one barrier separates lifetimes.
// Tripwires: VGPR <= 64, WRITE_SIZE == 6144.
// l semantics unchanged: l = sum of bf16_trunc(P).
// ---------------------------------------------------------------------------
__global__ __launch_bounds__(512) void attn_mfma(
    const unsigned short* __restrict__ qkv, const unsigned short* __restrict__ VT,
    const float* __restrict__ fsel_arr, const float* __restrict__ lw_p,
    const float* __restrict__ gw_p, unsigned short* __restrict__ attnb)
{
    // Union: Pbuf [8][16*72] ushort (18432 B) | Mrg [7][16][66] f32 (29568 B)
    __shared__ __align__(16) unsigned char SMEM[29568];

    const int tid = threadIdx.x;
    const int widx = tid >> 6, lane = tid & 63;
    const int lm = lane & 15, quad = lane >> 4;

    unsigned short* Pw = (unsigned short*)SMEM + widx * (16 * 72);
    float* MrgF = (float*)SMEM;
    // Mrg[slot][row][col], col 0..63 = O, 65 = l (64 unused)
    #define MRG(slot, row, col) MrgF[((((slot) * 16) + (row)) * 66) + (col)]

    const int strip = 127 - (int)(blockIdx.x / 24);   // heavy strips first
    const int bh = (int)(blockIdx.x % 24);
    const int h = bh % Hsz, b = bh / Hsz;
    const int i0 = strip * 16;

    const unsigned short* qkv_b = qkv + (size_t)b * Tsz * C3;

    // Q A-frags: A[m=lm][k=quad*8+j], two k-halves over d=0..63
    const unsigned short* qrow = qkv_b + (size_t)(i0 + lm) * C3 + h * 64 + quad * 8;
    const bf16x8 qf0 = *(const bf16x8*)qrow;
    const bf16x8 qf1 = *(const bf16x8*)(qrow + 32);

    float lacc[4];                 // per-lane partial row sums (one branch)
    f32x4 O[4];                    // one branch's output accumulator
    #pragma unroll
    for (int r = 0; r < 4; ++r) lacc[r] = 0.f;
    #pragma unroll
    for (int nt = 0; nt < 4; ++nt) O[nt] = f32x4{0.f, 0.f, 0.f, 0.f};

    const int jtd = i0 >> 6;                        // diagonal 64-tile
    const int jtl = (jtd - 4) > 0 ? (jtd - 4) : 0;  // first local tile

    if (widx < 6) {
        // ================= GLOBAL branch waves (0..5) =================
        for (int jt = widx; jt <= jtd; jt += 6) {
            const int j0 = jt * 64;
            const bool diag = (jt == jtd);

            const unsigned short* kb =
                qkv_b + (size_t)(j0 + lm) * C3 + Csz + h * 64 + quad * 8;
            #pragma unroll
            for (int nt = 0; nt < 4; ++nt) {
                bf16x8 k0v = *(const bf16x8*)(kb + (size_t)nt * 16 * C3);
                bf16x8 k1v = *(const bf16x8*)(kb + (size_t)nt * 16 * C3 + 32);
                f32x4 z = f32x4{0.f, 0.f, 0.f, 0.f};
                z = __builtin_amdgcn_mfma_f32_16x16x32_bf16(qf0, k0v, z, 0, 0, 0);
                z = __builtin_amdgcn_mfma_f32_16x16x32_bf16(qf1, k1v, z, 0, 0, 0);
                const float fsv = fsel_arr[b * Tsz + j0 + nt * 16 + lm];
                const int kj = j0 + nt * 16 + lm;
                #pragma unroll
                for (int r = 0; r < 4; ++r) {
                    float p = fast_exp2(z[r] * fsv);
                    if (diag) {
                        const int qi = i0 + quad * 4 + r;
                        p = (kj > qi) ? 0.f : p;
                    }
                    unsigned int u = __float_as_uint(p);
                    lacc[r] += __uint_as_float(u & 0xffff0000u);
                    Pw[(quad * 4 + r) * 72 + nt * 16 + lm] = (unsigned short)(u >> 16);
                }
            }

            const bf16x8 a0 = *(const bf16x8*)(&Pw[lm * 72 + quad * 8]);
            const bf16x8 a1 = *(const bf16x8*)(&Pw[lm * 72 + 32 + quad * 8]);
            const unsigned short* vb =
                VT + ((size_t)bh * 64 + lm) * Tsz + j0 + quad * 8;
            #pragma unroll
            for (int nt = 0; nt < 4; ++nt) {
                bf16x8 v0 = *(const bf16x8*)(vb + (size_t)nt * 16 * Tsz);
                bf16x8 v1 = *(const bf16x8*)(vb + (size_t)nt * 16 * Tsz + 32);
                O[nt] = __builtin_amdgcn_mfma_f32_16x16x32_bf16(a0, v0, O[nt], 0, 0, 0);
                O[nt] = __builtin_amdgcn_mfma_f32_16x16x32_bf16(a1, v1, O[nt], 0, 0, 0);
            }
        }
    } else {
        // ================= LOCAL branch waves (6,7) =================
        for (int jt = jtl + (widx - 6); jt <= jtd; jt += 2) {
            const int j0 = jt * 64;
            const bool diag = (jt == jtd);
            const bool flo = (jt == jtl);

            const unsigned short* kb =
                qkv_b + (size_t)(j0 + lm) * C3 + Csz + h * 64 + quad * 8;
            #pragma unroll
            for (int nt = 0; nt < 4; ++nt) {
                bf16x8 k0v = *(const bf16x8*)(kb + (size_t)nt * 16 * C3);
                bf16x8 k1v = *(const bf16x8*)(kb + (size_t)nt * 16 * C3 + 32);
                f32x4 z = f32x4{0.f, 0.f, 0.f, 0.f};
                z = __builtin_amdgcn_mfma_f32_16x16x32_bf16(qf0, k0v, z, 0, 0, 0);
                z = __builtin_amdgcn_mfma_f32_16x16x32_bf16(qf1, k1v, z, 0, 0, 0);
                const int kj = j0 + nt * 16 + lm;
                #pragma unroll
                for (int r = 0; r < 4; ++r) {
                    float p = fast_exp2(z[r]);
                    const int qi = i0 + quad * 4 + r;
                    if (diag) p = (kj > qi) ? 0.f : p;
                    if (flo)  p = (kj < qi - WIN) ? 0.f : p;
                    unsigned int u = __float_as_uint(p);
                    lacc[r] += __uint_as_float(u & 0xffff0000u);
                    Pw[(quad * 4 + r) * 72 + nt * 16 + lm] = (unsigned short)(u >> 16);
                }
            }

            const bf16x8 a0 = *(const bf16x8*)(&Pw[lm * 72 + quad * 8]);
            const bf16x8 a1 = *(const bf16x8*)(&Pw[lm * 72 + 32 + quad * 8]);
            const unsigned short* vb =
                VT + ((size_t)bh * 64 + lm) * Tsz + j0 + quad * 8;
            #pragma unroll
            for (int nt = 0; nt < 4; ++nt) {
                bf16x8 v0 = *(const bf16x8*)(vb + (size_t)nt * 16 * Tsz);
                bf16x8 v1 = *(const bf16x8*)(vb + (size_t)nt * 16 * Tsz + 32);
                O[nt] = __builtin_amdgcn_mfma_f32_16x16x32_bf16(a0, v0, O[nt], 0, 0, 0);
                O[nt] = __builtin_amdgcn_mfma_f32_16x16x32_bf16(a1, v1, O[nt], 0, 0, 0);
            }
        }
    }

    // ---- reduce l partials over the 16 lm lanes (butterfly; all lanes get sum)
    #pragma unroll
    for (int st = 1; st < 16; st <<= 1)
        #pragma unroll
        for (int r = 0; r < 4; ++r)
            lacc[r] += __shfl_xor(lacc[r], st);

    // ==== merge: waves 1..7 -> slots 0..6 (global 0..4, local 5,6) ====
    __syncthreads();          // Pbuf lifetime ends before Mrg overlay begins
    if (widx >= 1) {
        const int slot = widx - 1;
        #pragma unroll
        for (int r = 0; r < 4; ++r) {
            const int row = quad * 4 + r;
            #pragma unroll
            for (int nt = 0; nt < 4; ++nt)
                MRG(slot, row, nt * 16 + lm) = O[nt][r];
            if (lm == 0)
                MRG(slot, row, 65) = lacc[r];
        }
    }
    __syncthreads();

    if (widx == 0) {
        float wl = 1.f / (1.f + __expf(-lw_p[0]));
        float wg = 1.f / (1.f + __expf(-gw_p[0]));
        float ws = wl + wg;
        wl /= ws; wg /= ws;

        #pragma unroll
        for (int r = 0; r < 4; ++r) {
            const int row = quad * 4 + r;
            float l_g = lacc[r];
            #pragma unroll
            for (int s = 0; s < 5; ++s) l_g += MRG(s, row, 65);
            float l_l = MRG(5, row, 65) + MRG(6, row, 65);
            const float cg = wg / l_g;
            const float cl = wl / l_l;
            #pragma unroll
            for (int nt = 0; nt < 4; ++nt) {
                float og = O[nt][r];
                #pragma unroll
                for (int s = 0; s < 5; ++s) og += MRG(s, row, nt * 16 + lm);
                float ol = MRG(5, row, nt * 16 + lm) + MRG(6, row, nt * 16 + lm);
                float v = og * cg + ol * cl;
                attnb[(size_t)(b * Tsz + i0 + row) * Csz + h * 64 + nt * 16 + lm] =
                    f2b(v);
            }
        }
    }
    #undef MRG
}

// ---------------------------------------------------------------------------
extern "C" void kernel_launch(void* const* d_in, const int* in_sizes, int n_in,
                              void* d_out, int out_size, void* d_ws, size_t ws_size,
                              hipStream_t stream)
{
    const float* x          = (const float*)d_in[0];
    const float* mamba_raw  = (const float*)d_in[1];
    const float* c_attn_w   = (const float*)d_in[2];
    const float* c_attn_b   = (const float*)d_in[3];
    const float* c_proj_w   = (const float*)d_in[4];
    const float* c_proj_b   = (const float*)d_in[5];
    const float* ln_w       = (const float*)d_in[6];
    const float* ln_b       = (const float*)d_in[7];
    const float* mamba_sc   = (const float*)d_in[8];
    const float* sel_w      = (const float*)d_in[9];
    const float* sel_b      = (const float*)d_in[10];
    const float* local_w    = (const float*)d_in[11];
    const float* global_w   = (const float*)d_in[12];
    float* out = (float*)d_out;

    const int M = Bsz * Tsz;                 // 4096

    // Workspace layout (ushort units)
    unsigned short* xb    = (unsigned short*)d_ws;       // 4096*768
    unsigned short* wq    = xb + (size_t)M * Csz;        // 2304*768 (c_attn_w^T)
    unsigned short* wp    = wq + (size_t)C3 * Csz;       // 768*768  (c_proj_w^T)
    unsigned short* qkvb  = wp + (size_t)Csz * Csz;      // 4096*2304
    unsigned short* vt    = qkvb + (size_t)M * C3;       // 24*64*2048
    unsigned short* attnb = vt + (size_t)Bsz * Hsz * 64 * Tsz; // 4096*768
    float* sel = (float*)(attnb + (size_t)M * Csz);      // 4096

    // 1) conversions
    convert_bf16<<<(M * Csz / 4 + 255) / 256, 256, 0, stream>>>(x, xb, M * Csz / 4);
    {
        dim3 g(C3 / 32, Csz / 32);
        transpose_conv<<<g, 256, 0, stream>>>(c_attn_w, wq, Csz, C3);
    }
    {
        dim3 g(Csz / 32, Csz / 32);
        transpose_conv<<<g, 256, 0, stream>>>(c_proj_w, wp, Csz, Csz);
    }

    // 2) selector (outputs 0.5 + 0.5*sigmoid)
    sel_kernel<<<M, 256, 0, stream>>>(mamba_raw, ln_w, ln_b, mamba_sc,
                                      sel_w, sel_b, sel);

    // 3) QKV projection (bf16 out; Q cols pre-scaled by QSCALE)
    {
        dim3 g(C3 / 128, M / 128);
        gemm_bt_mfma<1><<<g, 256, 0, stream>>>(xb, wq, c_attn_b, qkvb,
                                               M, C3, Csz, Csz);
    }

    // 4) V transpose
    {
        dim3 g(Tsz / 32, 64 / 32, Bsz * Hsz);
        transpose_v<<<g, 256, 0, stream>>>(qkvb, vt);
    }

    // 5) attention (bf16 out): one block per strip per (b,h), 8 waves
    attn_mfma<<<128 * Hsz * Bsz, 512, 0, stream>>>(qkvb, vt, sel,
                                                   local_w, global_w, attnb);

    // 6) output projection (fp32 out, no scaling)
    {
        dim3 g(Csz / 128, M / 128);
        gemm_bt_mfma<0><<<g, 256, 0, stream>>>(attnb, wp, c_proj_b, out,
                                               M, Csz, Csz, 0);
    }
}

// Round 8
// 204.269 us; speedup vs baseline: 1.3826x; 1.3826x over previous
//
#include <hip/hip_runtime.h>
#include <math.h>

// Problem constants
#define Bsz 2
#define Tsz 2048
#define Csz 768
#define Hsz 12
#define C3  2304      // 3*C
#define WIN 256
#define LN_EPS 1e-5f

// Q pre-scale: D^-0.5 * log2(e), folded into the QKV GEMM epilogue so the
// attention kernel works in the exp2 domain with no per-element multiplies.
#define QSCALE 0.1803368801111137f

typedef short bf16x8 __attribute__((ext_vector_type(8)));  // 8 bf16 (4 VGPRs)
typedef float f32x4  __attribute__((ext_vector_type(4)));

// fp32 -> bf16 round-to-nearest-even
__device__ __forceinline__ unsigned short f2b(float f) {
    unsigned int u = __float_as_uint(f);
    u = (u + 0x7fffu + ((u >> 16) & 1u)) >> 16;
    return (unsigned short)u;
}

// raw v_exp_f32 (exp2). ocml exp2f without fast-math adds ~5 insts of
// denormal fixup; inputs here are |x| <~ 12, nothing denormal matters.
__device__ __forceinline__ float fast_exp2(float x) {
    float r;
    asm("v_exp_f32 %0, %1" : "=v"(r) : "v"(x));
    return r;
}

// ---------------------------------------------------------------------------
// Elementwise fp32 -> bf16 (4 elems/thread)
// ---------------------------------------------------------------------------
__global__ __launch_bounds__(256) void convert_bf16(
    const float* __restrict__ src, unsigned short* __restrict__ dst, int n4)
{
    int idx = blockIdx.x * 256 + threadIdx.x;
    if (idx >= n4) return;
    float4 v = *(const float4*)(src + (size_t)idx * 4);
    unsigned int lo = (unsigned int)f2b(v.x) | ((unsigned int)f2b(v.y) << 16);
    unsigned int hi = (unsigned int)f2b(v.z) | ((unsigned int)f2b(v.w) << 16);
    uint2 o; o.x = lo; o.y = hi;
    *(uint2*)(dst + (size_t)idx * 4) = o;
}

// ---------------------------------------------------------------------------
// fp32 [K][N] -> bf16 [N][K] (transpose + convert)
// ---------------------------------------------------------------------------
__global__ __launch_bounds__(256) void transpose_conv(
    const float* __restrict__ src, unsigned short* __restrict__ dst, int K, int N)
{
    __shared__ float tile[32][33];
    const int n0 = blockIdx.x * 32, k0 = blockIdx.y * 32;
    const int tx = threadIdx.x & 31, ty = threadIdx.x >> 5;   // 32 x 8
    #pragma unroll
    for (int p = 0; p < 4; ++p)
        tile[ty + p * 8][tx] = src[(size_t)(k0 + ty + p * 8) * N + n0 + tx];
    __syncthreads();
    #pragma unroll
    for (int p = 0; p < 4; ++p)
        dst[(size_t)(n0 + ty + p * 8) * K + k0 + tx] = f2b(tile[tx][ty + p * 8]);
}

// ---------------------------------------------------------------------------
// K fragment pre-pack: qkvb K rows -> KP in MFMA B-frag-linear order.
// KP[((bh*128 + kt)*2 + f)*512 + lane*8 + j]
//   = K[b][t = kt*16 + (lane&15)][h*64 + f*32 + (lane>>4)*8 + j]
// Each attn K-frag load then becomes base + lane*16B (fully coalesced 1KB).
// ---------------------------------------------------------------------------
__global__ __launch_bounds__(256) void pack_k(
    const unsigned short* __restrict__ qkv, unsigned short* __restrict__ KP)
{
    const int g = blockIdx.x * 4 + (threadIdx.x >> 6);   // frag group 0..6143
    const int lane = threadIdx.x & 63;
    const int lm = lane & 15, quad = lane >> 4;
    const int f = g & 1;
    const int kt = (g >> 1) & 127;
    const int bh = g >> 8;
    const int b = bh / Hsz, h = bh % Hsz;
    const unsigned short* src = qkv +
        (size_t)(b * Tsz + kt * 16 + lm) * C3 + Csz + h * 64 + f * 32 + quad * 8;
    bf16x8 v = *(const bf16x8*)src;
    *(bf16x8*)(KP + (size_t)g * 512 + lane * 8) = v;
}

// ---------------------------------------------------------------------------
// V fragment pre-pack (replaces transpose_v): qkvb V rows -> VP in MFMA
// B-frag-linear order.
// VP[((bh*64 + jt)*4 + nt)*512 + lane*8 + j]
//   = V[b][t = jt*32 + (lane>>4)*8 + j][h*64 + nt*16 + (lane&15)]
// ---------------------------------------------------------------------------
__global__ __launch_bounds__(256) void pack_v(
    const unsigned short* __restrict__ qkv, unsigned short* __restrict__ VP)
{
    __shared__ unsigned short tile[32][72];   // [t][d], padded
    const int g = blockIdx.x;                 // (bh, jt32) 0..1535
    const int jt = g & 63;
    const int bh = g >> 6;
    const int b = bh / Hsz, h = bh % Hsz;

    const int row = threadIdx.x >> 3, dc = (threadIdx.x & 7) * 8;
    *(bf16x8*)&tile[row][dc] = *(const bf16x8*)(
        qkv + (size_t)(b * Tsz + jt * 32 + row) * C3 + 2 * Csz + h * 64 + dc);
    __syncthreads();

    const int lane = threadIdx.x & 63, nt = threadIdx.x >> 6;
    const int lm = lane & 15, quad = lane >> 4;
    unsigned short tmp[8];
    #pragma unroll
    for (int j = 0; j < 8; ++j) tmp[j] = tile[quad * 8 + j][nt * 16 + lm];
    *(bf16x8*)(VP + ((size_t)(bh * 64 + jt) * 4 + nt) * 512 + lane * 8) =
        *(bf16x8*)tmp;
}

// ---------------------------------------------------------------------------
// fsel[r] = 0.5 + 0.5*sigmoid(mamba_scale * dot(LN(mamba_raw[r]), sel_w) + sel_b)
// ---------------------------------------------------------------------------
__global__ __launch_bounds__(256) void sel_kernel(
    const float* __restrict__ mr, const float* __restrict__ ln_w,
    const float* __restrict__ ln_b, const float* __restrict__ scale_p,
    const float* __restrict__ sel_w, const float* __restrict__ sel_b,
    float* __restrict__ sel)
{
    __shared__ float red1[256];
    __shared__ float red2[256];
    __shared__ float mu_sh, rstd_sh;

    const int r = blockIdx.x;
    const int tid = threadIdx.x;
    const float* row = mr + (size_t)r * Csz;

    float s = 0.f, s2 = 0.f;
    for (int c = tid; c < Csz; c += 256) {
        float x = row[c];
        s += x; s2 += x * x;
    }
    red1[tid] = s; red2[tid] = s2;
    __syncthreads();
    for (int st = 128; st > 0; st >>= 1) {
        if (tid < st) { red1[tid] += red1[tid + st]; red2[tid] += red2[tid + st]; }
        __syncthreads();
    }
    if (tid == 0) {
        float mu = red1[0] * (1.f / Csz);
        float var = red2[0] * (1.f / Csz) - mu * mu;
        mu_sh = mu;
        rstd_sh = rsqrtf(var + LN_EPS);
    }
    __syncthreads();
    const float mu = mu_sh, rstd = rstd_sh;

    float dot = 0.f;
    for (int c = tid; c < Csz; c += 256) {
        float xn = (row[c] - mu) * rstd * ln_w[c] + ln_b[c];
        dot += xn * sel_w[c];
    }
    red1[tid] = dot;
    __syncthreads();
    for (int st = 128; st > 0; st >>= 1) {
        if (tid < st) red1[tid] += red1[tid + st];
        __syncthreads();
    }
    if (tid == 0) {
        float z = scale_p[0] * red1[0] + sel_b[0];
        sel[r] = 0.5f + 0.5f / (1.f + __expf(-z));
    }
}

// ---------------------------------------------------------------------------
// bf16 MFMA GEMM, B^T input: C[M,N] = A[M,K] @ BT[N,K]^T + bias
// cols < scale_cols additionally scaled by QSCALE (folds attention q-scale,
// applied after bias -- matches reference (x@W+b)*scale).
// ---------------------------------------------------------------------------
template<int OUT_BF16>
__global__ __launch_bounds__(256) void gemm_bt_mfma(
    const unsigned short* __restrict__ A, const unsigned short* __restrict__ BT,
    const float* __restrict__ bias, void* __restrict__ Cout,
    int M, int N, int K, int scale_cols)
{
    __shared__ unsigned short As[128 * 32];
    __shared__ unsigned short Bs[128 * 32];

    const int tid = threadIdx.x;
    const int lane = tid & 63, widx = tid >> 6;
    const int lm = lane & 15, quad = lane >> 4;
    const int wm = widx >> 1, wn = widx & 1;
    const int m0 = blockIdx.y * 128, n0 = blockIdx.x * 128;

    f32x4 acc[4][4];
    #pragma unroll
    for (int mt = 0; mt < 4; ++mt)
        #pragma unroll
        for (int nt = 0; nt < 4; ++nt)
            acc[mt][nt] = f32x4{0.f, 0.f, 0.f, 0.f};

    int rowS[2], cS[2];
    #pragma unroll
    for (int t = 0; t < 2; ++t) {
        int idx = t * 256 + tid;
        rowS[t] = idx >> 2;
        cS[t] = idx & 3;
    }

    bf16x8 pa[2], pb[2];
    #pragma unroll
    for (int t = 0; t < 2; ++t) {
        pa[t] = *(const bf16x8*)(A + (size_t)(m0 + rowS[t]) * K + cS[t] * 8);
        pb[t] = *(const bf16x8*)(BT + (size_t)(n0 + rowS[t]) * K + cS[t] * 8);
    }

    const int nk = K / 32;
    for (int kt = 0; kt < nk; ++kt) {
        __syncthreads();
        #pragma unroll
        for (int t = 0; t < 2; ++t) {
            *(bf16x8*)(&As[rowS[t] * 32 + ((cS[t] ^ ((rowS[t] >> 1) & 3)) << 3)]) = pa[t];
            *(bf16x8*)(&Bs[rowS[t] * 32 + ((cS[t] ^ ((rowS[t] >> 1) & 3)) << 3)]) = pb[t];
        }
        __syncthreads();
        if (kt + 1 < nk) {
            int k0 = (kt + 1) * 32;
            #pragma unroll
            for (int t = 0; t < 2; ++t) {
                pa[t] = *(const bf16x8*)(A + (size_t)(m0 + rowS[t]) * K + k0 + cS[t] * 8);
                pb[t] = *(const bf16x8*)(BT + (size_t)(n0 + rowS[t]) * K + k0 + cS[t] * 8);
            }
        }
        bf16x8 af[4], bf[4];
        #pragma unroll
        for (int mt = 0; mt < 4; ++mt) {
            int m = wm * 64 + mt * 16 + lm;
            af[mt] = *(const bf16x8*)(&As[m * 32 + ((quad ^ ((m >> 1) & 3)) << 3)]);
        }
        #pragma unroll
        for (int nt = 0; nt < 4; ++nt) {
            int n = wn * 64 + nt * 16 + lm;
            bf[nt] = *(const bf16x8*)(&Bs[n * 32 + ((quad ^ ((n >> 1) & 3)) << 3)]);
        }
        #pragma unroll
        for (int mt = 0; mt < 4; ++mt)
            #pragma unroll
            for (int nt = 0; nt < 4; ++nt)
                acc[mt][nt] = __builtin_amdgcn_mfma_f32_16x16x32_bf16(
                    af[mt], bf[nt], acc[mt][nt], 0, 0, 0);
    }

    float bv[4], scl[4];
    #pragma unroll
    for (int nt = 0; nt < 4; ++nt) {
        bv[nt] = bias[n0 + wn * 64 + nt * 16 + lm];
        scl[nt] = ((n0 + wn * 64 + nt * 16) < scale_cols) ? QSCALE : 1.0f;
    }

    #pragma unroll
    for (int mt = 0; mt < 4; ++mt) {
        #pragma unroll
        for (int nt = 0; nt < 4; ++nt) {
            int col = n0 + wn * 64 + nt * 16 + lm;
            #pragma unroll
            for (int r = 0; r < 4; ++r) {
                int row = m0 + wm * 64 + mt * 16 + quad * 4 + r;
                float v = (acc[mt][nt][r] + bv[nt]) * scl[nt];
                if (OUT_BF16)
                    ((unsigned short*)Cout)[(size_t)row * N + col] = f2b(v);
                else
                    ((float*)Cout)[(size_t)row * N + col] = v;
            }
        }
    }
}

// ---------------------------------------------------------------------------
// MFMA flash attention, dual softmax, NO-MAX variant.
// R7 change: K and V frags now load from the pre-packed frag-linear buffers
// KP/VP: every frag load is base + tile*1KB + lane*16B -> 64 lanes x 16B
// fully contiguous (8 L2 lines/instruction vs ~32 for the strided qkv/VT
// reads). Theory: the attn loop is bound by L2 request bandwidth (issue work
// ~7us at full rate, measured 112+us, pipes <30% combined, extra occupancy
// made it WORSE in R4/R6) -> cutting lines/instruction 4x attacks the actual
// limiter. Structure otherwise identical to R5's passing kernel (dual-branch
// 4 waves, stride 4, LDS union, VALU-l, fast_exp2, mask elision; no register
// prefetch - compiler sinks it, R5; no launch_bounds min-occ arg - spills,
// R1/R3). Tripwires: WRITE_SIZE == 6144, VGPR 65..128.
// LDS: 18432 B (Pbuf; Mrg overlaid).
// ---------------------------------------------------------------------------
__global__ __launch_bounds__(256) void attn_mfma(
    const unsigned short* __restrict__ qkv, const unsigned short* __restrict__ KP,
    const unsigned short* __restrict__ VP, const float* __restrict__ fsel_arr,
    const float* __restrict__ lw_p, const float* __restrict__ gw_p,
    unsigned short* __restrict__ attnb)
{
    // Union: Pbuf [4][2][16*72] ushort (18432 B) | Mrg [2][2][16][66] f32 (16896 B)
    __shared__ __align__(16) unsigned char SMEM[18432];

    const int tid = threadIdx.x;
    const int widx = tid >> 6, lane = tid & 63;
    const int lm = lane & 15, quad = lane >> 4;

    unsigned short* Pg = (unsigned short*)SMEM + (widx * 2 + 0) * (16 * 72);
    unsigned short* Pl = (unsigned short*)SMEM + (widx * 2 + 1) * (16 * 72);
    float* MrgF = (float*)SMEM;
    // Mrg[slot][branch][row][col], col 0..63 = O, 65 = l (64 unused)
    #define MRG(slot, br, row, col) MrgF[((((slot) * 2 + (br)) * 16 + (row)) * 66) + (col)]

    const int strip = 127 - (int)(blockIdx.x / 24);   // heavy strips first
    const int bh = (int)(blockIdx.x % 24);
    const int h = bh % Hsz, b = bh / Hsz;
    const int i0 = strip * 16;

    const unsigned short* qkv_b = qkv + (size_t)b * Tsz * C3;
    const unsigned short* KPb = KP + (size_t)bh * 131072 + lane * 8;  // bh*128*2*512
    const unsigned short* VPb = VP + (size_t)bh * 131072 + lane * 8;  // bh*64*4*512

    // Q A-frags: A[m=lm][k=quad*8+j], two k-halves over d=0..63
    const unsigned short* qrow = qkv_b + (size_t)(i0 + lm) * C3 + h * 64 + quad * 8;
    const bf16x8 qf0 = *(const bf16x8*)qrow;
    const bf16x8 qf1 = *(const bf16x8*)(qrow + 32);

    float l_g[4], l_l[4];                       // per-lane partial row sums
    f32x4 Og[4], Ol[4];
    #pragma unroll
    for (int r = 0; r < 4; ++r) { l_g[r] = 0.f; l_l[r] = 0.f; }
    #pragma unroll
    for (int nt = 0; nt < 4; ++nt) {
        Og[nt] = f32x4{0.f, 0.f, 0.f, 0.f};
        Ol[nt] = f32x4{0.f, 0.f, 0.f, 0.f};
    }

    const int jtd = i0 >> 6;                        // diagonal 64-tile
    const int jtl = (jtd - 4) > 0 ? (jtd - 4) : 0;  // first local tile

    for (int jt = widx; jt <= jtd; jt += 4) {
        const int j0 = jt * 64;
        const bool diag = (jt == jtd);
        const bool firstloc = (jt == jtl) && !diag;
        const bool loc = (jt >= jtl);

        // ---- K frags from KP (frag-linear, fully coalesced) ----
        // group ((bh*128 + (j0>>4)+nt)*2 + f): offset ((j0>>4)+nt)*1024 + f*512
        const unsigned short* kp = KPb + (size_t)(j0 >> 4) * 1024;
        bf16x8 kc0[4], kc1[4];
        #pragma unroll
        for (int nt = 0; nt < 4; ++nt) {
            kc0[nt] = *(const bf16x8*)(kp + nt * 1024);
            kc1[nt] = *(const bf16x8*)(kp + nt * 1024 + 512);
        }

        // ---- QK^T ----
        f32x4 s[4];
        #pragma unroll
        for (int nt = 0; nt < 4; ++nt) {
            f32x4 z = f32x4{0.f, 0.f, 0.f, 0.f};
            z = __builtin_amdgcn_mfma_f32_16x16x32_bf16(qf0, kc0[nt], z, 0, 0, 0);
            z = __builtin_amdgcn_mfma_f32_16x16x32_bf16(qf1, kc1[nt], z, 0, 0, 0);
            s[nt] = z;
        }

        float fs[4];
        #pragma unroll
        for (int nt = 0; nt < 4; ++nt)
            fs[nt] = fsel_arr[b * Tsz + j0 + nt * 16 + lm];

        // ---- global branch: P = exp2(s*fs); causal mask only on diag ----
        if (diag) {
            #pragma unroll
            for (int r = 0; r < 4; ++r) {
                const int qi = i0 + quad * 4 + r;
                #pragma unroll
                for (int nt = 0; nt < 4; ++nt) {
                    const int kj = j0 + nt * 16 + lm;
                    float p = fast_exp2(s[nt][r] * fs[nt]);
                    p = (kj > qi) ? 0.f : p;
                    unsigned int u = __float_as_uint(p);
                    l_g[r] += __uint_as_float(u & 0xffff0000u);
                    Pg[(quad * 4 + r) * 72 + nt * 16 + lm] = (unsigned short)(u >> 16);
                }
            }
        } else {
            #pragma unroll
            for (int r = 0; r < 4; ++r)
                #pragma unroll
                for (int nt = 0; nt < 4; ++nt) {
                    float p = fast_exp2(s[nt][r] * fs[nt]);
                    unsigned int u = __float_as_uint(p);
                    l_g[r] += __uint_as_float(u & 0xffff0000u);
                    Pg[(quad * 4 + r) * 72 + nt * 16 + lm] = (unsigned short)(u >> 16);
                }
        }

        // ---- local branch: P = exp2(s); masks only at diag / first tile ----
        if (loc) {
            if (diag) {
                #pragma unroll
                for (int r = 0; r < 4; ++r) {
                    const int qi = i0 + quad * 4 + r;
                    #pragma unroll
                    for (int nt = 0; nt < 4; ++nt) {
                        const int kj = j0 + nt * 16 + lm;
                        float p = fast_exp2(s[nt][r]);
                        p = (kj > qi || kj < qi - WIN) ? 0.f : p;
                        unsigned int u = __float_as_uint(p);
                        l_l[r] += __uint_as_float(u & 0xffff0000u);
                        Pl[(quad * 4 + r) * 72 + nt * 16 + lm] = (unsigned short)(u >> 16);
                    }
                }
            } else if (firstloc) {
                #pragma unroll
                for (int r = 0; r < 4; ++r) {
                    const int qi = i0 + quad * 4 + r;
                    #pragma unroll
                    for (int nt = 0; nt < 4; ++nt) {
                        const int kj = j0 + nt * 16 + lm;
                        float p = fast_exp2(s[nt][r]);
                        p = (kj < qi - WIN) ? 0.f : p;
                        unsigned int u = __float_as_uint(p);
                        l_l[r] += __uint_as_float(u & 0xffff0000u);
                        Pl[(quad * 4 + r) * 72 + nt * 16 + lm] = (unsigned short)(u >> 16);
                    }
                }
            } else {
                #pragma unroll
                for (int r = 0; r < 4; ++r)
                    #pragma unroll
                    for (int nt = 0; nt < 4; ++nt) {
                        float p = fast_exp2(s[nt][r]);
                        unsigned int u = __float_as_uint(p);
                        l_l[r] += __uint_as_float(u & 0xffff0000u);
                        Pl[(quad * 4 + r) * 72 + nt * 16 + lm] = (unsigned short)(u >> 16);
                    }
            }
        }

        // ---- P A-frags: issue all reads together, once per tile ----
        const bf16x8 ag0 = *(const bf16x8*)(&Pg[lm * 72 + quad * 8]);
        const bf16x8 ag1 = *(const bf16x8*)(&Pg[lm * 72 + 32 + quad * 8]);
        bf16x8 al0 = {}, al1 = {};
        if (loc) {
            al0 = *(const bf16x8*)(&Pl[lm * 72 + quad * 8]);
            al1 = *(const bf16x8*)(&Pl[lm * 72 + 32 + quad * 8]);
        }

        // ---- V frags from VP (frag-linear, fully coalesced) ----
        // group ((bh*64 + (j0>>5))*4 + nt): offset (j0>>5)*2048 + nt*512
        const unsigned short* vp = VPb + (size_t)(j0 >> 5) * 2048;
        #pragma unroll
        for (int nt = 0; nt < 4; ++nt) {
            bf16x8 v0 = *(const bf16x8*)(vp + nt * 512);
            bf16x8 v1 = *(const bf16x8*)(vp + 2048 + nt * 512);
            Og[nt] = __builtin_amdgcn_mfma_f32_16x16x32_bf16(ag0, v0, Og[nt], 0, 0, 0);
            Og[nt] = __builtin_amdgcn_mfma_f32_16x16x32_bf16(ag1, v1, Og[nt], 0, 0, 0);
            if (loc) {
                Ol[nt] = __builtin_amdgcn_mfma_f32_16x16x32_bf16(al0, v0, Ol[nt], 0, 0, 0);
                Ol[nt] = __builtin_amdgcn_mfma_f32_16x16x32_bf16(al1, v1, Ol[nt], 0, 0, 0);
            }
        }
    }

    // ---- reduce l partials over the 16 lm lanes (butterfly, all lanes get sum)
    #pragma unroll
    for (int st = 1; st < 16; st <<= 1) {
        #pragma unroll
        for (int r = 0; r < 4; ++r) {
            l_g[r] += __shfl_xor(l_g[r], st);
            l_l[r] += __shfl_xor(l_l[r], st);
        }
    }

    // ==== 2-slot pairwise merge tree over the Pbuf/Mrg union ====
    auto write_slot = [&](int slot) {
        #pragma unroll
        for (int r = 0; r < 4; ++r) {
            const int row = quad * 4 + r;
            #pragma unroll
            for (int nt = 0; nt < 4; ++nt) {
                MRG(slot, 0, row, nt * 16 + lm) = Og[nt][r];
                MRG(slot, 1, row, nt * 16 + lm) = Ol[nt][r];
            }
            if (lm == 0) {
                MRG(slot, 0, row, 65) = l_g[r];
                MRG(slot, 1, row, 65) = l_l[r];
            }
        }
    };
    auto combine_slot = [&](int slot) {
        #pragma unroll
        for (int r = 0; r < 4; ++r) {
            const int row = quad * 4 + r;
            {
                l_g[r] += MRG(slot, 0, row, 65);
                #pragma unroll
                for (int nt = 0; nt < 4; ++nt)
                    Og[nt][r] += MRG(slot, 0, row, nt * 16 + lm);
            }
            {
                l_l[r] += MRG(slot, 1, row, 65);
                #pragma unroll
                for (int nt = 0; nt < 4; ++nt)
                    Ol[nt][r] += MRG(slot, 1, row, nt * 16 + lm);
            }
        }
    };

    __syncthreads();          // Pbuf lifetime ends before Mrg overlay begins
    if (widx == 1) write_slot(0);
    if (widx == 3) write_slot(1);
    __syncthreads();
    if (widx == 0) combine_slot(0);
    if (widx == 2) combine_slot(1);
    __syncthreads();
    if (widx == 2) write_slot(0);
    __syncthreads();

    if (widx == 0) {
        combine_slot(0);      // wave 0 now holds the full-strip sums

        float wl = 1.f / (1.f + __expf(-lw_p[0]));
        float wg = 1.f / (1.f + __expf(-gw_p[0]));
        float ws = wl + wg;
        wl /= ws; wg /= ws;

        #pragma unroll
        for (int r = 0; r < 4; ++r) {
            const int row = quad * 4 + r;
            const float cg = wg / l_g[r];
            const float cl = wl / l_l[r];
            #pragma unroll
            for (int nt = 0; nt < 4; ++nt) {
                float v = Og[nt][r] * cg + Ol[nt][r] * cl;
                attnb[(size_t)(b * Tsz + i0 + row) * Csz + h * 64 + nt * 16 + lm] =
                    f2b(v);
            }
        }
    }
    #undef MRG
}

// ---------------------------------------------------------------------------
extern "C" void kernel_launch(void* const* d_in, const int* in_sizes, int n_in,
                              void* d_out, int out_size, void* d_ws, size_t ws_size,
                              hipStream_t stream)
{
    const float* x          = (const float*)d_in[0];
    const float* mamba_raw  = (const float*)d_in[1];
    const float* c_attn_w   = (const float*)d_in[2];
    const float* c_attn_b   = (const float*)d_in[3];
    const float* c_proj_w   = (const float*)d_in[4];
    const float* c_proj_b   = (const float*)d_in[5];
    const float* ln_w       = (const float*)d_in[6];
    const float* ln_b       = (const float*)d_in[7];
    const float* mamba_sc   = (const float*)d_in[8];
    const float* sel_w      = (const float*)d_in[9];
    const float* sel_b      = (const float*)d_in[10];
    const float* local_w    = (const float*)d_in[11];
    const float* global_w   = (const float*)d_in[12];
    float* out = (float*)d_out;

    const int M = Bsz * Tsz;                 // 4096

    // Workspace layout (ushort units)
    unsigned short* xb    = (unsigned short*)d_ws;       // 4096*768
    unsigned short* wq    = xb + (size_t)M * Csz;        // 2304*768 (c_attn_w^T)
    unsigned short* wp    = wq + (size_t)C3 * Csz;       // 768*768  (c_proj_w^T)
    unsigned short* qkvb  = wp + (size_t)Csz * Csz;      // 4096*2304
    unsigned short* kpb   = qkvb + (size_t)M * C3;       // 24*128*2*512 = 3.15M
    unsigned short* vpb   = kpb + (size_t)24 * 131072;   // 24*64*4*512 = 3.15M
    unsigned short* attnb = vpb + (size_t)24 * 131072;   // 4096*768
    float* sel = (float*)(attnb + (size_t)M * Csz);      // 4096

    // 1) conversions
    convert_bf16<<<(M * Csz / 4 + 255) / 256, 256, 0, stream>>>(x, xb, M * Csz / 4);
    {
        dim3 g(C3 / 32, Csz / 32);
        transpose_conv<<<g, 256, 0, stream>>>(c_attn_w, wq, Csz, C3);
    }
    {
        dim3 g(Csz / 32, Csz / 32);
        transpose_conv<<<g, 256, 0, stream>>>(c_proj_w, wp, Csz, Csz);
    }

    // 2) selector (outputs 0.5 + 0.5*sigmoid)
    sel_kernel<<<M, 256, 0, stream>>>(mamba_raw, ln_w, ln_b, mamba_sc,
                                      sel_w, sel_b, sel);

    // 3) QKV projection (bf16 out; Q cols pre-scaled by QSCALE)
    {
        dim3 g(C3 / 128, M / 128);
        gemm_bt_mfma<1><<<g, 256, 0, stream>>>(xb, wq, c_attn_b, qkvb,
                                               M, C3, Csz, Csz);
    }

    // 4) K/V fragment pre-pack (frag-linear layouts for the attn hot loop)
    pack_k<<<1536, 256, 0, stream>>>(qkvb, kpb);
    pack_v<<<1536, 256, 0, stream>>>(qkvb, vpb);

    // 5) attention (bf16 out): one block per strip per (b,h)
    attn_mfma<<<128 * Hsz * Bsz, 256, 0, stream>>>(qkvb, kpb, vpb, sel,
                                                   local_w, global_w, attnb);

    // 6) output projection (fp32 out, no scaling)
    {
        dim3 g(Csz / 128, M / 128);
        gemm_bt_mfma<0><<<g, 256, 0, stream>>>(attnb, wp, c_proj_b, out,
                                               M, Csz, Csz, 0);
    }
}